// Round 4
// baseline (2519.014 us; speedup 1.0000x reference)
//
#include <hip/hip_runtime.h>
#include <stdint.h>
#include <stddef.h>

typedef __bf16 bf16_t;
typedef __bf16 bf16x8 __attribute__((ext_vector_type(8)));
typedef _Float16 halfx2 __attribute__((ext_vector_type(2)));
typedef float floatx4 __attribute__((ext_vector_type(4)));

#define N_ROWS 16384
#define DIM    1024

__device__ inline bf16x8 cvt_f32x8_bf16(const float* __restrict__ p) {
    floatx4 a = *(const floatx4*)p;
    floatx4 b = *(const floatx4*)(p + 4);
    bf16x8 r;
    r[0] = (bf16_t)a[0]; r[1] = (bf16_t)a[1]; r[2] = (bf16_t)a[2]; r[3] = (bf16_t)a[3];
    r[4] = (bf16_t)b[0]; r[5] = (bf16_t)b[1]; r[6] = (bf16_t)b[2]; r[7] = (bf16_t)b[3];
    return r;
}

// C[m,n] = sum_k A[m,k] * B[n,k] + bias[n]   (B^T GEMM; row-major, K contiguous)
// N=K=1024. 128x128 tile, BK=32, 256 threads (4 waves, 2x2 of 64x64).
// A: f32 (inputs) or bf16 (ws avg). B/bias: always f32 (weights). C: bf16 (ws) or f32 (d_out).
template<bool AF32, bool CF32, bool RELU>
__global__ __launch_bounds__(256) void gemm_bt(const void* __restrict__ Av,
                                               const float* __restrict__ B,
                                               const float* __restrict__ bias,
                                               void* __restrict__ Cv) {
    const int K = 1024, NN = 1024;
    const int bm = blockIdx.y, bn = blockIdx.x;
    const int t = threadIdx.x;
    const int lane = t & 63;
    const int w = t >> 6;
    const int wm = w & 1, wn = w >> 1;

    __shared__ __align__(16) bf16_t sA[128 * 32];
    __shared__ __align__(16) bf16_t sB[128 * 32];

    floatx4 acc[4][4] = {};

    // thread t stages rows (t>>2) and 64+(t>>2), k-cols (t&3)*8..+8 (8 elements each)
    const int rowA = t >> 2;
    const int colk = (t & 3) * 8;
    const size_t aOff = (size_t)(bm * 128 + rowA) * K + colk;
    const float*  gAf = (const float*)Av  + aOff;
    const bf16_t* gAh = (const bf16_t*)Av + aOff;
    const float*  gBf = B + (size_t)(bn * 128 + rowA) * K + colk;
    const int ldsOff = rowA * 32 + colk;  // == t*8 elements

    // MFMA A/B fragment: row = lane&15, k = (lane>>4)*8 .. +8  [m92/m97 verified]
    const int aoff = (lane & 15) * 32 + (lane >> 4) * 8;

    for (int kt = 0; kt < K / 32; ++kt) {
        bf16x8 a0, a1, b0, b1;
        if constexpr (AF32) {
            a0 = cvt_f32x8_bf16(gAf);
            a1 = cvt_f32x8_bf16(gAf + (size_t)64 * K);
            gAf += 32;
        } else {
            a0 = *(const bf16x8*)gAh;
            a1 = *(const bf16x8*)(gAh + (size_t)64 * K);
            gAh += 32;
        }
        b0 = cvt_f32x8_bf16(gBf);
        b1 = cvt_f32x8_bf16(gBf + (size_t)64 * K);
        gBf += 32;

        __syncthreads();  // previous iteration's readers done
        *(bf16x8*)&sA[ldsOff]        = a0;
        *(bf16x8*)&sA[ldsOff + 2048] = a1;   // +64 rows
        *(bf16x8*)&sB[ldsOff]        = b0;
        *(bf16x8*)&sB[ldsOff + 2048] = b1;
        __syncthreads();

        bf16x8 af[4], bfr[4];
#pragma unroll
        for (int i = 0; i < 4; ++i)
            af[i] = *(const bf16x8*)&sA[(wm * 64 + i * 16) * 32 + aoff];
#pragma unroll
        for (int j = 0; j < 4; ++j)
            bfr[j] = *(const bf16x8*)&sB[(wn * 64 + j * 16) * 32 + aoff];
#pragma unroll
        for (int i = 0; i < 4; ++i)
#pragma unroll
            for (int j = 0; j < 4; ++j)
                acc[i][j] = __builtin_amdgcn_mfma_f32_16x16x32_bf16(af[i], bfr[j], acc[i][j], 0, 0, 0);
    }

    // epilogue: C/D layout col=lane&15, row=(lane>>4)*4 + r  [verified m89]
    const int col = lane & 15;
    const int rbase = (lane >> 4) * 4;
#pragma unroll
    for (int j = 0; j < 4; ++j) {
        const int gn = bn * 128 + wn * 64 + j * 16 + col;
        const float bj = bias[gn];
#pragma unroll
        for (int i = 0; i < 4; ++i) {
            const int gm0 = bm * 128 + wm * 64 + i * 16 + rbase;
#pragma unroll
            for (int r = 0; r < 4; ++r) {
                float v = acc[i][j][r] + bj;
                if (RELU) v = v > 0.f ? v : 0.f;
                const size_t idx = (size_t)(gm0 + r) * NN + gn;
                if constexpr (CF32) ((float*)Cv)[idx] = v;
                else                ((bf16_t*)Cv)[idx] = (bf16_t)v;
            }
        }
    }
}

// One block per row n (within chunk). 192 threads = 3 waves; wave a = attention a.
// Lane = e (score column); softmax over d (axis=1) is register-local per lane.
// LDS: 18432 + 25344 + 13056 = 56832 B.
__global__ __launch_bounds__(192) void attn_kernel(const bf16_t* __restrict__ proj,
                                                   size_t slot_stride,
                                                   bf16_t* __restrict__ avg) {
    const int n = blockIdx.x;
    const int t = threadIdx.x;
    const int a = t >> 6;
    const int lane = t & 63;

    __shared__ __align__(16) bf16_t sQKV[9][1024];
    __shared__ _Float16 sW[3][64][66];  // w[d][e]; read stride 66: (lane+e/2)%32, 2-way = free
    __shared__ float    sO[3][64][17];  // o[d][h]; stride 17: conflict-free

    for (int c = t; c < 9 * 128; c += 192) {
        int s   = c >> 7;
        int off = (c & 127) * 8;
        *(bf16x8*)&sQKV[s][off] =
            *(const bf16x8*)(proj + (size_t)s * slot_stride + (size_t)n * DIM + off);
    }
    __syncthreads();

    const bf16_t* sQ = sQKV[3 * a];
    const bf16_t* sK = sQKV[3 * a + 1];
    const bf16_t* sV = sQKV[3 * a + 2];

    // K column e: kreg[h] = K[e,h] = row_k[h*64+e]
    float kreg[16];
#pragma unroll
    for (int h = 0; h < 16; ++h) kreg[h] = (float)sK[h * 64 + lane];

    // s[d] = (1/8) * sum_h Q[d,h]*K[e,h];  Q[d,h] = row_q[h*64+d] (broadcast reads)
    float s[64];
#pragma unroll
    for (int d = 0; d < 64; ++d) s[d] = 0.f;
#pragma unroll
    for (int h = 0; h < 16; ++h) {
#pragma unroll
        for (int j = 0; j < 8; ++j) {
            bf16x8 q8 = *(const bf16x8*)&sQ[h * 64 + j * 8];
#pragma unroll
            for (int u = 0; u < 8; ++u)
                s[j * 8 + u] += (float)q8[u] * kreg[h];
        }
    }

    float m = -1e30f;
#pragma unroll
    for (int d = 0; d < 64; ++d) { s[d] *= 0.125f; m = fmaxf(m, s[d]); }
    float sum = 0.f;
#pragma unroll
    for (int d = 0; d < 64; ++d) { s[d] = __expf(s[d] - m); sum += s[d]; }
    const float inv = 1.f / sum;
#pragma unroll
    for (int d = 0; d < 64; ++d) sW[a][d][lane] = (_Float16)(s[d] * inv);

    __syncthreads();

    // lane = d now: o[d,h] = sum_e w[d,e] * V[e,h];  V[e,h] = row_v[h*64+e]
    float wreg[64];
    {
        const halfx2* wrow = (const halfx2*)&sW[a][lane][0];  // 4B-aligned (132*lane % 4 == 0)
#pragma unroll
        for (int e2 = 0; e2 < 32; ++e2) {
            halfx2 hv = wrow[e2];
            wreg[2 * e2]     = (float)hv[0];
            wreg[2 * e2 + 1] = (float)hv[1];
        }
    }

    float o[16];
#pragma unroll
    for (int h = 0; h < 16; ++h) o[h] = 0.f;
#pragma unroll
    for (int h = 0; h < 16; ++h) {
#pragma unroll
        for (int j = 0; j < 8; ++j) {
            bf16x8 v8 = *(const bf16x8*)&sV[h * 64 + j * 8];
#pragma unroll
            for (int u = 0; u < 8; ++u)
                o[h] += (float)v8[u] * wreg[j * 8 + u];
        }
    }
#pragma unroll
    for (int h = 0; h < 16; ++h) sO[a][lane][h] = o[h];

    __syncthreads();

    // out[n, h*64+d] = mean_a o_a[d,h]
    for (int idx = t; idx < 1024; idx += 192) {
        int d = idx & 63, h = idx >> 6;
        float v = (sO[0][d][h] + sO[1][d][h] + sO[2][d][h]) * (1.f / 3.f);
        avg[(size_t)n * DIM + idx] = (bf16_t)v;
    }
}

extern "C" void kernel_launch(void* const* d_in, const int* in_sizes, int n_in,
                              void* d_out, int out_size, void* d_ws, size_t ws_size,
                              hipStream_t stream) {
    // Reference dtypes are float32 (jnp.float32) — read as float, write float.
    const float* query = (const float*)d_in[0];
    const float* key_  = (const float*)d_in[1];
    const float* value = (const float*)d_in[2];
    const float* Wq1 = (const float*)d_in[3];  const float* bq1 = (const float*)d_in[4];
    const float* Wk1 = (const float*)d_in[5];  const float* bk1 = (const float*)d_in[6];
    const float* Wv1 = (const float*)d_in[7];  const float* bv1 = (const float*)d_in[8];
    const float* Wq2 = (const float*)d_in[9];  const float* bq2 = (const float*)d_in[10];
    const float* Wk2 = (const float*)d_in[11]; const float* bk2 = (const float*)d_in[12];
    const float* Wv2 = (const float*)d_in[13]; const float* bv2 = (const float*)d_in[14];
    const float* Wq3 = (const float*)d_in[15]; const float* bq3 = (const float*)d_in[16];
    const float* Wk3 = (const float*)d_in[17]; const float* bk3 = (const float*)d_in[18];
    const float* Wv3 = (const float*)d_in[19]; const float* bv3 = (const float*)d_in[20];
    const float* Wo  = (const float*)d_in[21]; const float* bo  = (const float*)d_in[22];

    // slots 0..8 = Q1 K1 V1 Q2 K2 V2 Q3 K3 V3 (cross-wired per reference)
    const float* As[9] = {query, value, key_, value, key_, query, key_, query, value};
    const float* Bs[9] = {Wq1,   Wk2,   Wv1,  Wq2,   Wk1,  Wv2,   Wq3,  Wk3,   Wv3};
    const float* bs[9] = {bq1,   bk2,   bv1,  bq2,   bk1,  bv2,   bq3,  bk3,   bv3};

    // Chunk rows so bf16 scratch = 10 * CH * 1024 * 2 bytes fits ws_size.
    const size_t per_row = 10 * DIM * sizeof(bf16_t);  // 20480 B
    size_t ch = ws_size / per_row;
    if (ch > N_ROWS) ch = N_ROWS;
    int CH = (int)((ch / 128) * 128);
    if (CH < 128) CH = 128;  // require ws_size >= 2.62 MB

    bf16_t* proj = (bf16_t*)d_ws;                  // 9 * CH * DIM (bf16)
    bf16_t* avgb = proj + (size_t)9 * CH * DIM;    // CH * DIM (bf16)
    const size_t sstride = (size_t)CH * DIM;

    for (int r0 = 0; r0 < N_ROWS; r0 += CH) {
        int rows = (N_ROWS - r0 < CH) ? (N_ROWS - r0) : CH;  // multiple of 128

        for (int i = 0; i < 9; ++i) {
            gemm_bt<true, false, false><<<dim3(8, rows / 128), 256, 0, stream>>>(
                As[i] + (size_t)r0 * DIM, Bs[i], bs[i],
                proj + (size_t)i * sstride);
        }

        attn_kernel<<<dim3(rows), 192, 0, stream>>>(proj, sstride, avgb);

        gemm_bt<false, true, true><<<dim3(8, rows / 128), 256, 0, stream>>>(
            avgb, Wo, bo, (float*)d_out + (size_t)r0 * DIM);
    }
}